// Round 13
// baseline (399.827 us; speedup 1.0000x reference)
//
#include <hip/hip_runtime.h>
#include <cmath>

#define HF 128
#define EPB 2048

namespace {

typedef __attribute__((ext_vector_type(8))) short short8;
typedef __attribute__((ext_vector_type(4))) float f32x4;
typedef unsigned long long u64;

inline int cdiv(int a, int b) { return (a + b - 1) / b; }

__device__ inline unsigned short f2bf(float x) {
    unsigned u = __float_as_uint(x);
    return (unsigned short)((u + 0x7fffu + ((u >> 16) & 1u)) >> 16);
}
__device__ inline float bf2f(unsigned short u) {
    return __uint_as_float((unsigned)u << 16);
}
__device__ inline float bflo(unsigned v) { return __uint_as_float(v << 16); }
__device__ inline float bfhi(unsigned v) { return __uint_as_float(v & 0xffff0000u); }

#define FIXS 4194304.0f            /* 2^22 */
#define FIXINV 2.384185791015625e-07f
#define SUMMASK ((1ULL << 40) - 1)

// ---- MFMA GEMM body: out[N,128](bf16) = [A1|A2][N,K] @ Wpk (+bias)(+relu) ----
template <int K, bool AF32>
__device__ __forceinline__ void gemm_dev(int bid, const void* __restrict__ A1v, int lda1,
                                         const void* __restrict__ A2v, int lda2,
                                         const unsigned short* __restrict__ wpk,
                                         const float* __restrict__ bias, int relu,
                                         unsigned short* __restrict__ out, int N) {
    const int t = threadIdx.x;
    const int wv = t >> 6, lane = t & 63;
    const int l15 = lane & 15, lhi = lane >> 4;
    const int rbase = bid * 128 + wv * 32;

    f32x4 acc[2][8];
#pragma unroll
    for (int i = 0; i < 2; ++i)
#pragma unroll
        for (int g = 0; g < 8; ++g) acc[i][g] = {0.f, 0.f, 0.f, 0.f};

    int r[2];
#pragma unroll
    for (int ri = 0; ri < 2; ++ri) {
        int rr = rbase + ri * 16 + l15;
        r[ri] = (rr < N) ? rr : (N - 1);
    }

    for (int kc = 0; kc < K / 32; ++kc) {
        int kb = kc * 32 + lhi * 8;
        short8 a[2];
#pragma unroll
        for (int ri = 0; ri < 2; ++ri) {
            if (AF32) {
                const float* A = (const float*)A1v;
                const float* p = A + (size_t)r[ri] * lda1 + kb;
                float4 f0 = *reinterpret_cast<const float4*>(p);
                float4 f1 = *reinterpret_cast<const float4*>(p + 4);
                a[ri][0] = (short)f2bf(f0.x); a[ri][1] = (short)f2bf(f0.y);
                a[ri][2] = (short)f2bf(f0.z); a[ri][3] = (short)f2bf(f0.w);
                a[ri][4] = (short)f2bf(f1.x); a[ri][5] = (short)f2bf(f1.y);
                a[ri][6] = (short)f2bf(f1.z); a[ri][7] = (short)f2bf(f1.w);
            } else {
                const unsigned short* base;
                int kk, ld;
                if (K == 256 && kb >= 128) { base = (const unsigned short*)A2v; kk = kb - 128; ld = lda2; }
                else                       { base = (const unsigned short*)A1v; kk = kb;       ld = lda1; }
                a[ri] = *reinterpret_cast<const short8*>(base + (size_t)r[ri] * ld + kk);
            }
        }
        const unsigned short* wb = wpk + (size_t)(kc * 8) * 512 + lane * 8;
#pragma unroll
        for (int g = 0; g < 8; ++g) {
            short8 b = *reinterpret_cast<const short8*>(wb + (size_t)g * 512);
            acc[0][g] = __builtin_amdgcn_mfma_f32_16x16x32_bf16(a[0], b, acc[0][g], 0, 0, 0);
            acc[1][g] = __builtin_amdgcn_mfma_f32_16x16x32_bf16(a[1], b, acc[1][g], 0, 0, 0);
        }
    }

#pragma unroll
    for (int ri = 0; ri < 2; ++ri) {
#pragma unroll
        for (int g = 0; g < 8; ++g) {
            int col = l15 + g * 16;
            float bb = bias ? bias[col] : 0.f;
#pragma unroll
            for (int e = 0; e < 4; ++e) {
                int rr = rbase + ri * 16 + lhi * 4 + e;
                if (rr < N) {
                    float v = acc[ri][g][e] + bb;
                    if (relu) v = fmaxf(v, 0.f);
                    out[(size_t)rr * 128 + col] = f2bf(v);
                }
            }
        }
    }
}

template <int K, bool AF32>
__global__ void k_mfma_gemm(const void* __restrict__ A1v, int lda1,
                            const void* __restrict__ A2v, int lda2,
                            const unsigned short* __restrict__ wpk,
                            const float* __restrict__ bias, int relu,
                            unsigned short* __restrict__ out, int N) {
    gemm_dev<K, AF32>(blockIdx.x, A1v, lda1, A2v, lda2, wpk, bias, relu, out, N);
}

// ---- device pieces ----
__device__ __forceinline__ void hist_dev(int e, int E, const int* __restrict__ col,
                                         const float* __restrict__ ew,
                                         u64* __restrict__ dc, unsigned* __restrict__ rank) {
    if (e < E) {
        u64 v = (1ULL << 40) | (u64)(ew[e] * FIXS + 0.5f);
        u64 old = atomicAdd(&dc[col[e]], v);
        rank[e] = (unsigned)(old >> 40);
    }
}

__device__ inline void scan256(int* s, int v, int gid, int n, int* __restrict__ excl,
                               int* __restrict__ partial, int pb) {
    s[threadIdx.x] = v;
    __syncthreads();
    for (int off = 1; off < 256; off <<= 1) {
        int t = (threadIdx.x >= off) ? s[threadIdx.x - off] : 0;
        __syncthreads();
        s[threadIdx.x] += t;
        __syncthreads();
    }
    if (gid < n) excl[gid] = s[threadIdx.x] - v;
    if (threadIdx.x == 255) partial[pb] = s[255];
}

// packed CSR record: {coef_bf16:16 | src:16}; coef = ew * dinv[src]
__device__ __forceinline__ void fill_dev(int b, int t, const int* __restrict__ row,
                                         const int* __restrict__ col, const float* __restrict__ ew,
                                         const unsigned* __restrict__ rank,
                                         const float* __restrict__ dinv, const int* __restrict__ rp,
                                         unsigned* __restrict__ ed, int E, int Nn) {
    int xcd = b & 7, chunk = b >> 3;
    int lo = (int)((long long)Nn * xcd >> 3), hi = (int)((long long)Nn * (xcd + 1) >> 3);
    int base = chunk * EPB;
#pragma unroll
    for (int i = 0; i < EPB; i += 256) {
        int e = base + i + t;
        if (e < E) {
            int c = col[e];
            if (c >= lo && c < hi) {
                int r = row[e];
                ed[rp[c] + rank[e]] =
                    (unsigned)r | ((unsigned)f2bf(ew[e] * dinv[r]) << 16);
            }
        }
    }
}

// gather: one wave/dest; 16-deep row-load pipeline with edge-index prefetch.
// acc = dinv*xw[c] + sum coef*xw[src]; out = relu(acc*dinv + b)
__device__ __forceinline__ void gather_dev(int b, const unsigned* __restrict__ xw, int n,
                                           const int* __restrict__ rp,
                                           const unsigned* __restrict__ ed,
                                           const float* __restrict__ dinv,
                                           const float* __restrict__ bias,
                                           unsigned* __restrict__ out) {
    int wid = (b * 256 + (int)threadIdx.x) >> 6;
    if (wid >= n) return;
    int lane = threadIdx.x & 63;
    int s = rp[wid], e = rp[wid + 1];
    float d = dinv[wid];
    unsigned v = xw[(size_t)wid * 64 + lane];
    float ax = bflo(v) * d, ay = bfhi(v) * d;
    float bx = 0.f, by = 0.f, cx = 0.f, cy = 0.f, dx = 0.f, dy = 0.f;
    float ex = 0.f, ey = 0.f, fx = 0.f, fy = 0.f, gx = 0.f, gy = 0.f, hx = 0.f, hy = 0.f;
    int i = s;
    for (; (i & 3) != 0 && i < e; ++i) {
        unsigned q = ed[i];
        unsigned v0 = xw[(size_t)(q & 0xffffu) * 64 + lane];
        float c0 = bfhi(q);
        ax += c0 * bflo(v0); ay += c0 * bfhi(v0);
    }
    if (i + 16 <= e) {
        // software pipeline: indices for the current batch in registers; prefetch next.
        uint4 qa = *reinterpret_cast<const uint4*>(ed + i);
        uint4 qb = *reinterpret_cast<const uint4*>(ed + i + 4);
        uint4 qc = *reinterpret_cast<const uint4*>(ed + i + 8);
        uint4 qd = *reinterpret_cast<const uint4*>(ed + i + 12);
        for (; i + 16 <= e; ) {
            // issue 16 independent row loads
            unsigned v0 = xw[(size_t)(qa.x & 0xffffu) * 64 + lane];
            unsigned v1 = xw[(size_t)(qa.y & 0xffffu) * 64 + lane];
            unsigned v2 = xw[(size_t)(qa.z & 0xffffu) * 64 + lane];
            unsigned v3 = xw[(size_t)(qa.w & 0xffffu) * 64 + lane];
            unsigned v4 = xw[(size_t)(qb.x & 0xffffu) * 64 + lane];
            unsigned v5 = xw[(size_t)(qb.y & 0xffffu) * 64 + lane];
            unsigned v6 = xw[(size_t)(qb.z & 0xffffu) * 64 + lane];
            unsigned v7 = xw[(size_t)(qb.w & 0xffffu) * 64 + lane];
            unsigned v8 = xw[(size_t)(qc.x & 0xffffu) * 64 + lane];
            unsigned v9 = xw[(size_t)(qc.y & 0xffffu) * 64 + lane];
            unsigned vA = xw[(size_t)(qc.z & 0xffffu) * 64 + lane];
            unsigned vB = xw[(size_t)(qc.w & 0xffffu) * 64 + lane];
            unsigned vC = xw[(size_t)(qd.x & 0xffffu) * 64 + lane];
            unsigned vD = xw[(size_t)(qd.y & 0xffffu) * 64 + lane];
            unsigned vE = xw[(size_t)(qd.z & 0xffffu) * 64 + lane];
            unsigned vF = xw[(size_t)(qd.w & 0xffffu) * 64 + lane];
            float c0 = bfhi(qa.x), c1 = bfhi(qa.y), c2 = bfhi(qa.z), c3 = bfhi(qa.w);
            float c4 = bfhi(qb.x), c5 = bfhi(qb.y), c6 = bfhi(qb.z), c7 = bfhi(qb.w);
            float c8 = bfhi(qc.x), c9 = bfhi(qc.y), cA = bfhi(qc.z), cB = bfhi(qc.w);
            float cC = bfhi(qd.x), cD = bfhi(qd.y), cE = bfhi(qd.z), cF = bfhi(qd.w);
            i += 16;
            // prefetch next batch's indices before consuming rows
            if (i + 16 <= e) {
                qa = *reinterpret_cast<const uint4*>(ed + i);
                qb = *reinterpret_cast<const uint4*>(ed + i + 4);
                qc = *reinterpret_cast<const uint4*>(ed + i + 8);
                qd = *reinterpret_cast<const uint4*>(ed + i + 12);
            }
            ax += c0 * bflo(v0); ay += c0 * bfhi(v0);
            bx += c1 * bflo(v1); by += c1 * bfhi(v1);
            cx += c2 * bflo(v2); cy += c2 * bfhi(v2);
            dx += c3 * bflo(v3); dy += c3 * bfhi(v3);
            ex += c4 * bflo(v4); ey += c4 * bfhi(v4);
            fx += c5 * bflo(v5); fy += c5 * bfhi(v5);
            gx += c6 * bflo(v6); gy += c6 * bfhi(v6);
            hx += c7 * bflo(v7); hy += c7 * bfhi(v7);
            ax += c8 * bflo(v8); ay += c8 * bfhi(v8);
            bx += c9 * bflo(v9); by += c9 * bfhi(v9);
            cx += cA * bflo(vA); cy += cA * bfhi(vA);
            dx += cB * bflo(vB); dy += cB * bfhi(vB);
            ex += cC * bflo(vC); ey += cC * bfhi(vC);
            fx += cD * bflo(vD); fy += cD * bfhi(vD);
            gx += cE * bflo(vE); gy += cE * bfhi(vE);
            hx += cF * bflo(vF); hy += cF * bfhi(vF);
        }
    }
    if (i + 8 <= e) {
        uint4 q0 = *reinterpret_cast<const uint4*>(ed + i);
        uint4 q1 = *reinterpret_cast<const uint4*>(ed + i + 4);
        unsigned v0 = xw[(size_t)(q0.x & 0xffffu) * 64 + lane];
        unsigned v1 = xw[(size_t)(q0.y & 0xffffu) * 64 + lane];
        unsigned v2 = xw[(size_t)(q0.z & 0xffffu) * 64 + lane];
        unsigned v3 = xw[(size_t)(q0.w & 0xffffu) * 64 + lane];
        unsigned v4 = xw[(size_t)(q1.x & 0xffffu) * 64 + lane];
        unsigned v5 = xw[(size_t)(q1.y & 0xffffu) * 64 + lane];
        unsigned v6 = xw[(size_t)(q1.z & 0xffffu) * 64 + lane];
        unsigned v7 = xw[(size_t)(q1.w & 0xffffu) * 64 + lane];
        float c0 = bfhi(q0.x), c1 = bfhi(q0.y), c2 = bfhi(q0.z), c3 = bfhi(q0.w);
        float c4 = bfhi(q1.x), c5 = bfhi(q1.y), c6 = bfhi(q1.z), c7 = bfhi(q1.w);
        ax += c0 * bflo(v0); ay += c0 * bfhi(v0);
        bx += c1 * bflo(v1); by += c1 * bfhi(v1);
        cx += c2 * bflo(v2); cy += c2 * bfhi(v2);
        dx += c3 * bflo(v3); dy += c3 * bfhi(v3);
        ex += c4 * bflo(v4); ey += c4 * bfhi(v4);
        fx += c5 * bflo(v5); fy += c5 * bfhi(v5);
        gx += c6 * bflo(v6); gy += c6 * bfhi(v6);
        hx += c7 * bflo(v7); hy += c7 * bfhi(v7);
        i += 8;
    }
    if (i + 4 <= e) {
        uint4 q0 = *reinterpret_cast<const uint4*>(ed + i);
        unsigned v0 = xw[(size_t)(q0.x & 0xffffu) * 64 + lane];
        unsigned v1 = xw[(size_t)(q0.y & 0xffffu) * 64 + lane];
        unsigned v2 = xw[(size_t)(q0.z & 0xffffu) * 64 + lane];
        unsigned v3 = xw[(size_t)(q0.w & 0xffffu) * 64 + lane];
        float c0 = bfhi(q0.x), c1 = bfhi(q0.y), c2 = bfhi(q0.z), c3 = bfhi(q0.w);
        ax += c0 * bflo(v0); ay += c0 * bfhi(v0);
        bx += c1 * bflo(v1); by += c1 * bfhi(v1);
        cx += c2 * bflo(v2); cy += c2 * bfhi(v2);
        dx += c3 * bflo(v3); dy += c3 * bfhi(v3);
        i += 4;
    }
    for (; i < e; ++i) {
        unsigned q = ed[i];
        unsigned v0 = xw[(size_t)(q & 0xffffu) * 64 + lane];
        float c0 = bfhi(q);
        ax += c0 * bflo(v0); ay += c0 * bfhi(v0);
    }
    ax += bx + cx + dx + ex + fx + gx + hx;
    ay += by + cy + dy + ey + fy + gy + hy;
    float2 bb = *reinterpret_cast<const float2*>(bias + lane * 2);
    ax = fmaxf(ax * d + bb.x, 0.f);
    ay = fmaxf(ay * d + bb.y, 0.f);
    out[(size_t)wid * 64 + lane] = (unsigned)f2bf(ax) | ((unsigned)f2bf(ay) << 16);
}

// ---- kernels ----
// K0: pack_w + bstart
__global__ void k_prep0(const float* __restrict__ w0, const float* __restrict__ w1,
                        const float* __restrict__ w2, const float* __restrict__ w3,
                        const float* __restrict__ w4, const float* __restrict__ w5,
                        unsigned short* __restrict__ wpk,
                        const int* __restrict__ b0, int n0, const int* __restrict__ b1,
                        int n1, int B, int* __restrict__ bst0, int* __restrict__ bst1) {
    int b = blockIdx.x, t = threadIdx.x;
    if (b < 576) {
        int idx = b * 256 + t;
        const float* src; int local;
        if      (idx < 16384)  { src = w0; local = idx; }
        else if (idx < 32768)  { src = w1; local = idx - 16384; }
        else if (idx < 65536)  { src = w2; local = idx - 32768; }
        else if (idx < 98304)  { src = w3; local = idx - 65536; }
        else if (idx < 114688) { src = w4; local = idx - 98304; }
        else                   { src = w5; local = idx - 114688; }
        int e = local & 7, lane = (local >> 3) & 63, g = (local >> 9) & 7, kc = local >> 12;
        int colw = (lane & 15) + 16 * g;
        int k = kc * 32 + ((lane >> 4) << 3) + e;
        wpk[idx] = f2bf(src[k * 128 + colw]);
        return;
    }
    int idx = t;
    if (idx < 2 * (B + 1)) {
        int which = idx > B;
        int bb = which ? idx - (B + 1) : idx;
        const int* arr = which ? b1 : b0;
        int lo = 0, hi = which ? n1 : n0;
        while (lo < hi) {
            int mid = (lo + hi) >> 1;
            if (arr[mid] < bb) lo = mid + 1; else hi = mid;
        }
        (which ? bst1 : bst0)[bb] = lo;
    }
}

// K1: GEMM1 || hist g0
__global__ void k_prep1(const float* __restrict__ x, const unsigned short* __restrict__ wpk,
                        unsigned short* __restrict__ xw, int N0gemm, int nbG,
                        const int* __restrict__ col0, const float* __restrict__ ew0,
                        u64* __restrict__ dc0, unsigned* __restrict__ rank0, int E0) {
    int b = blockIdx.x;
    if (b < nbG) {
        gemm_dev<128, true>(b, x, 128, nullptr, 0, wpk, nullptr, 0, xw, N0gemm);
        return;
    }
    b -= nbG;
    hist_dev(b * 256 + (int)threadIdx.x, E0, col0, ew0, dc0, rank0);
}

// K2: scan1(g0) + dinv0
__global__ void k_scanA(const u64* __restrict__ dc0, int* __restrict__ rp0,
                        int* __restrict__ part0, float* __restrict__ dinv0, int n0) {
    __shared__ int s[256];
    int gid = blockIdx.x * 256 + threadIdx.x;
    int v = (gid < n0) ? (int)(dc0[gid] >> 40) : 0;
    scan256(s, v, gid, n0, rp0, part0, blockIdx.x);
    if (gid < n0) dinv0[gid] = rsqrtf(1.0f + (float)(dc0[gid] & SUMMASK) * FIXINV);
}

__global__ void k_scan2a(int* __restrict__ p0, int nb0) {
    __shared__ int s[256];
    int v = (threadIdx.x < nb0) ? p0[threadIdx.x] : 0;
    s[threadIdx.x] = v;
    __syncthreads();
    for (int off = 1; off < 256; off <<= 1) {
        int t = (threadIdx.x >= off) ? s[threadIdx.x - off] : 0;
        __syncthreads();
        s[threadIdx.x] += t;
        __syncthreads();
    }
    if (threadIdx.x < nb0) p0[threadIdx.x] = s[threadIdx.x] - v;
}

__global__ void k_scan3a(int* __restrict__ rp0, const int* __restrict__ part0, int n0, int tot) {
    int gid = blockIdx.x * 256 + threadIdx.x;
    if (gid < n0) rp0[gid] += part0[blockIdx.x];
    if (gid == 0) rp0[n0] = tot;
}

// fill g0
__global__ void k_fill0(const int* __restrict__ row0, const int* __restrict__ col0,
                        const float* __restrict__ ew0, const unsigned* __restrict__ rank0,
                        const float* __restrict__ dinv0, const int* __restrict__ rp0,
                        unsigned* __restrict__ ed0, int E0, int N0n) {
    fill_dev(blockIdx.x, threadIdx.x, row0, col0, ew0, rank0, dinv0, rp0, ed0, E0, N0n);
}

// gather1 + hist(g1) + hist(cover)
__global__ void k_gather_hist(const unsigned* __restrict__ xw, int n,
                              const int* __restrict__ rp, const unsigned* __restrict__ ed,
                              const float* __restrict__ dinv, const float* __restrict__ bias,
                              unsigned* __restrict__ out, int G,
                              const int* __restrict__ col1, const float* __restrict__ ew1,
                              u64* __restrict__ dc1, unsigned* __restrict__ rank1,
                              int E1, int nb1,
                              const int* __restrict__ ccol, int* __restrict__ ccnt,
                              unsigned* __restrict__ rankc, int A) {
    int b = blockIdx.x;
    if (b < G) { gather_dev(b, xw, n, rp, ed, dinv, bias, out); return; }
    b -= G;
    int t = threadIdx.x;
    if (b < nb1) { hist_dev(b * 256 + t, E1, col1, ew1, dc1, rank1); return; }
    b -= nb1;
    int e = b * 256 + t;
    if (e < A) rankc[e] = (unsigned)atomicAdd(&ccnt[ccol[e]], 1);
}

// gemm2 + scan1(g1)+dinv1 + scan1(cover)
__global__ void k_gemm_scan(const void* __restrict__ A1v, const unsigned short* __restrict__ wpk,
                            unsigned short* __restrict__ out, int N, int nbG,
                            const u64* __restrict__ dc1, int* __restrict__ rp1,
                            int* __restrict__ part1, float* __restrict__ dinv1, int n1, int nbs1,
                            const int* __restrict__ ccnt, int* __restrict__ crp,
                            int* __restrict__ cpart, int nc) {
    __shared__ int s[256];
    int b = blockIdx.x;
    if (b < nbG) {
        gemm_dev<128, false>(b, A1v, 128, nullptr, 0, wpk, nullptr, 0, out, N);
        return;
    }
    b -= nbG;
    if (b < nbs1) {
        int gid = b * 256 + threadIdx.x;
        int v = (gid < n1) ? (int)(dc1[gid] >> 40) : 0;
        scan256(s, v, gid, n1, rp1, part1, b);
        if (gid < n1) dinv1[gid] = rsqrtf(1.0f + (float)(dc1[gid] & SUMMASK) * FIXINV);
        return;
    }
    b -= nbs1;
    {
        int gid = b * 256 + threadIdx.x;
        int v = (gid < nc) ? ccnt[gid] : 0;
        scan256(s, v, gid, nc, crp, cpart, b);
    }
}

__global__ void k_scan2b(int* __restrict__ p1, int nb1, int* __restrict__ p2, int nb2) {
    __shared__ int s[256];
    int* p = (blockIdx.x == 0) ? p1 : p2;
    int nb = (blockIdx.x == 0) ? nb1 : nb2;
    int v = (threadIdx.x < nb) ? p[threadIdx.x] : 0;
    s[threadIdx.x] = v;
    __syncthreads();
    for (int off = 1; off < 256; off <<= 1) {
        int t = (threadIdx.x >= off) ? s[threadIdx.x - off] : 0;
        __syncthreads();
        s[threadIdx.x] += t;
        __syncthreads();
    }
    if (threadIdx.x < nb) p[threadIdx.x] = s[threadIdx.x] - v;
}

__global__ void k_scan3b(int* __restrict__ rp1, const int* __restrict__ part1, int n1, int tot1,
                         int nb1, int* __restrict__ crp, const int* __restrict__ cpart,
                         int nc, int totc) {
    int b = blockIdx.x, t = threadIdx.x;
    if (b < nb1) {
        int gid = b * 256 + t;
        if (gid < n1) rp1[gid] += part1[b];
        if (gid == 0) rp1[n1] = tot1;
        return;
    }
    b -= nb1;
    int gid = b * 256 + t;
    if (gid < nc) crp[gid] += cpart[b];
    if (gid == 0) crp[nc] = totc;
}

// gather2 + fill(g1) + fill(cover, u16 srcs)
__global__ void k_gather_fill(const unsigned* __restrict__ xw, int n,
                              const int* __restrict__ rp, const unsigned* __restrict__ ed,
                              const float* __restrict__ dinv, const float* __restrict__ bias,
                              unsigned* __restrict__ out, int G,
                              const int* __restrict__ row1, const int* __restrict__ col1,
                              const float* __restrict__ ew1, const unsigned* __restrict__ rank1,
                              const float* __restrict__ dinv1, const int* __restrict__ rp1,
                              unsigned* __restrict__ ed1, int E1, int N1n, int g1b,
                              const int* __restrict__ crow, const int* __restrict__ ccol,
                              const unsigned* __restrict__ rankc, const int* __restrict__ crp,
                              unsigned short* __restrict__ csrcs, int A) {
    int b = blockIdx.x, t = threadIdx.x;
    if (b < G) { gather_dev(b, xw, n, rp, ed, dinv, bias, out); return; }
    b -= G;
    if (b < g1b) { fill_dev(b, t, row1, col1, ew1, rank1, dinv1, rp1, ed1, E1, N1n); return; }
    b -= g1b;
    {
        int xcd = b & 7, chunk = b >> 3;
        int lo = (int)((long long)N1n * xcd >> 3), hi = (int)((long long)N1n * (xcd + 1) >> 3);
        int base = chunk * EPB;
#pragma unroll
        for (int i = 0; i < EPB; i += 256) {
            int e = base + i + t;
            if (e < A) {
                int c = ccol[e];
                if (c >= lo && c < hi) csrcs[crp[c] + rankc[e]] = (unsigned short)crow[e];
            }
        }
    }
}

// plain gather
__global__ void k_gather(const unsigned* __restrict__ xw, int n, const int* __restrict__ rp,
                         const unsigned* __restrict__ ed, const float* __restrict__ dinv,
                         const float* __restrict__ bias, unsigned* __restrict__ out) {
    gather_dev(blockIdx.x, xw, n, rp, ed, dinv, bias, out);
}

// fused: batch pool (g0) + cover gather; h bf16 >= 0
__global__ void k_pool_cover(const unsigned short* __restrict__ h, const int* __restrict__ bst,
                             float* __restrict__ psum, float* __restrict__ pmax, int nsplit,
                             int nbpool, const unsigned* __restrict__ h32,
                             const int* __restrict__ crp,
                             const unsigned short* __restrict__ csrcs,
                             unsigned* __restrict__ h2, int n1) {
    int t = threadIdx.x;
    if ((int)blockIdx.x < nbpool) {
        int blk = blockIdx.x;
        int b = blk / nsplit, sub = (blk % nsplit) * 2 + (t >> 7);
        int col = t & 127;
        int r0 = bst[b], r1 = bst[b + 1];
        float sum = 0.f, mx = 0.f;
        for (int r = r0 + sub; r < r1; r += 2 * nsplit) {
            float v = bf2f(h[(size_t)r * HF + col]);
            sum += v;
            mx = fmaxf(mx, v);
        }
        atomicAdd(&psum[b * HF + col], sum);
        atomicMax(reinterpret_cast<int*>(&pmax[b * HF + col]), __float_as_int(mx));
        return;
    }
    int wid = (((int)blockIdx.x - nbpool) * 256 + t) >> 6;
    if (wid >= n1) return;
    int lane = t & 63;
    int s = crp[wid], e = crp[wid + 1];
    float sx = 0.f, sy = 0.f, mx = 0.f, my = 0.f;
    for (int i = s; i < e; ++i) {
        unsigned v = h32[(size_t)csrcs[i] * 64 + lane];
        float vx = bflo(v), vy = bfhi(v);
        sx += vx; sy += vy;
        mx = fmaxf(mx, vx); my = fmaxf(my, vy);
    }
    h2[(size_t)wid * 128 + lane]      = (unsigned)f2bf(sx) | ((unsigned)f2bf(sy) << 16);
    h2[(size_t)wid * 128 + 64 + lane] = (unsigned)f2bf(mx) | ((unsigned)f2bf(my) << 16);
}

__global__ void k_pool256(const unsigned short* __restrict__ h, const int* __restrict__ bst,
                          float* __restrict__ psum, float* __restrict__ pmax, int nsplit) {
    int t = threadIdx.x;
    int blk = blockIdx.x;
    int b = blk / nsplit, sub = (blk % nsplit) * 2 + (t >> 7);
    int col = t & 127;
    int r0 = bst[b], r1 = bst[b + 1];
    float sum = 0.f, mx = 0.f;
    for (int r = r0 + sub; r < r1; r += 2 * nsplit) {
        float v = bf2f(h[(size_t)r * HF + col]);
        sum += v;
        mx = fmaxf(mx, v);
    }
    atomicAdd(&psum[b * HF + col], sum);
    atomicMax(reinterpret_cast<int*>(&pmax[b * HF + col]), __float_as_int(mx));
}

__global__ void k_head(const float* __restrict__ p0s, const float* __restrict__ p0m,
                       const float* __restrict__ p1s, const float* __restrict__ p1m,
                       const float* __restrict__ gamma, const float* __restrict__ beta,
                       const float* __restrict__ w1, const float* __restrict__ b1,
                       const float* __restrict__ w2, const float* __restrict__ b2,
                       float* __restrict__ out) {
    __shared__ float z[512];
    __shared__ float z1[128];
    __shared__ float lg[10];
    int b = blockIdx.x, t = threadIdx.x;
    const float s = rsqrtf(1.0f + 1e-5f);
    z[t]       = p0s[b * 128 + t] * (gamma[t] * s)       + beta[t];
    z[128 + t] = p0m[b * 128 + t] * (gamma[128 + t] * s) + beta[128 + t];
    z[256 + t] = p1s[b * 128 + t] * (gamma[256 + t] * s) + beta[256 + t];
    z[384 + t] = p1m[b * 128 + t] * (gamma[384 + t] * s) + beta[384 + t];
    __syncthreads();
    float acc = b1[t];
    for (int k = 0; k < 512; ++k) acc += z[k] * w1[k * 128 + t];
    z1[t] = fmaxf(acc, 0.f);
    __syncthreads();
    if (t < 10) {
        float a2 = b2[t];
        for (int k = 0; k < 128; ++k) a2 += z1[k] * w2[k * 10 + t];
        lg[t] = a2;
    }
    __syncthreads();
    if (t == 0) {
        float m = lg[0];
        for (int c = 1; c < 10; ++c) m = fmaxf(m, lg[c]);
        float e[10], ssum = 0.f;
        for (int c = 0; c < 10; ++c) { e[c] = expf(lg[c] - m); ssum += e[c]; }
        for (int c = 0; c < 10; ++c) out[b * 10 + c] = e[c] / ssum;
    }
}

} // namespace

extern "C" void kernel_launch(void* const* d_in, const int* in_sizes, int n_in,
                              void* d_out, int out_size, void* d_ws, size_t ws_size,
                              hipStream_t stream) {
    const float* x      = (const float*)d_in[0];
    const int*   ei0    = (const int*)d_in[1];
    const float* ew0    = (const float*)d_in[2];
    const int*   batch0 = (const int*)d_in[3];
    const int*   crow   = (const int*)d_in[4];
    const int*   ccol   = (const int*)d_in[5];
    const int*   ei1    = (const int*)d_in[6];
    const float* ew1    = (const float*)d_in[7];
    const int*   batch1 = (const int*)d_in[8];
    const float* w_in1  = (const float*)d_in[9];
    const float* b_in1  = (const float*)d_in[10];
    const float* w_in2  = (const float*)d_in[11];
    const float* b_in2  = (const float*)d_in[12];
    const float* w_inl  = (const float*)d_in[13];
    const float* b_inl  = (const float*)d_in[14];
    const float* w_b1   = (const float*)d_in[15];
    const float* b_b1   = (const float*)d_in[16];
    const float* w_b2   = (const float*)d_in[17];
    const float* b_b2   = (const float*)d_in[18];
    const float* w_bl   = (const float*)d_in[19];
    const float* b_bl   = (const float*)d_in[20];
    const float* gamma  = (const float*)d_in[21];
    const float* beta   = (const float*)d_in[22];
    const float* w_l1   = (const float*)d_in[23];
    const float* b_l1   = (const float*)d_in[24];
    const float* w_l2   = (const float*)d_in[25];
    const float* b_l2   = (const float*)d_in[26];

    const int N0 = in_sizes[0] / 128;
    const int E0 = in_sizes[2];
    const int A  = in_sizes[4];
    const int E1 = in_sizes[7];
    const int N1 = in_sizes[8];
    const int B  = out_size / 10;

    const int* row0 = ei0;
    const int* col0 = ei0 + E0;
    const int* row1 = ei1;
    const int* col1 = ei1 + E1;

    // ---- workspace layout ----
    char* wsp = (char*)d_ws;
    size_t off = 0;
    auto alloc = [&](size_t bytes) -> char* {
        char* p = wsp + off;
        off += (bytes + 255) & ~(size_t)255;
        return p;
    };
    // zero region: dc0, dc1, ccnt, pools
    u64*  dc0  = (u64*)alloc((size_t)N0 * 8);
    u64*  dc1  = (u64*)alloc((size_t)N1 * 8);
    int*  ccnt = (int*)alloc((size_t)N1 * 4);
    float* p0s = (float*)alloc((size_t)B * HF * 4 * 4);
    float* p0m = p0s + (size_t)B * HF;
    float* p1s = p0m + (size_t)B * HF;
    float* p1m = p1s + (size_t)B * HF;
    size_t zero_bytes = off;

    unsigned* xw  = (unsigned*)alloc((size_t)N0 * 64 * 4);
    unsigned* x1  = (unsigned*)alloc((size_t)N0 * 64 * 4);
    unsigned* x2  = (unsigned*)alloc((size_t)N0 * 64 * 4);
    unsigned* h   = (unsigned*)alloc((size_t)N0 * 64 * 4);
    unsigned* h2  = (unsigned*)alloc((size_t)N1 * 128 * 4);
    unsigned short* wpk = (unsigned short*)alloc(147456 * 2);
    float* dinv0 = (float*)alloc((size_t)N0 * 4);
    float* dinv1 = (float*)alloc((size_t)N1 * 4);
    int*   rp0   = (int*)alloc(((size_t)N0 + 1) * 4);
    int*   rp1   = (int*)alloc(((size_t)N1 + 1) * 4);
    int*   crp   = (int*)alloc(((size_t)N1 + 1) * 4);
    int*   part0 = (int*)alloc(256 * 4);
    int*   part1 = (int*)alloc(256 * 4);
    int*   cpart = (int*)alloc(256 * 4);
    unsigned* ed0 = (unsigned*)alloc((size_t)E0 * 4);
    unsigned* ed1 = (unsigned*)alloc((size_t)E1 * 4);
    unsigned short* csrcs = (unsigned short*)alloc((size_t)A * 2);
    unsigned* rank0 = (unsigned*)alloc((size_t)E0 * 4);
    unsigned* rank1 = (unsigned*)alloc((size_t)E1 * 4);
    unsigned* rankc = (unsigned*)alloc((size_t)A * 4);
    int*   bst0  = (int*)alloc((size_t)(B + 1) * 4);
    int*   bst1  = (int*)alloc((size_t)(B + 1) * 4);
    (void)ws_size; (void)n_in;

    const int NSPLIT = 16;
    const int nbG0 = cdiv(N0, 128), nbG1 = cdiv(N1, 128);
    const int nbE0 = cdiv(E0, 256), nbE1 = cdiv(E1, 256), nbC = cdiv(A, 256);
    const int nbs0 = cdiv(N0, 256), nbs1 = cdiv(N1, 256), nbsc = cdiv(N1, 256);
    const int g0f = cdiv(E0, EPB) * 8, g1f = cdiv(E1, EPB) * 8, gcf = cdiv(A, EPB) * 8;
    const int G0 = cdiv(N0, 4), G1 = cdiv(N1, 4);

    hipMemsetAsync(dc0, 0, zero_bytes, stream);

    k_prep0<<<577, 256, 0, stream>>>(w_in1, w_in2, w_inl, w_b1, w_b2, w_bl, wpk,
                                     batch0, N0, batch1, N1, B, bst0, bst1);

    // GEMM1 || hist g0
    k_prep1<<<nbG0 + nbE0, 256, 0, stream>>>(x, wpk, (unsigned short*)xw, N0, nbG0,
                                             col0, ew0, dc0, rank0, E0);

    k_scanA<<<nbs0, 256, 0, stream>>>(dc0, rp0, part0, dinv0, N0);
    k_scan2a<<<1, 256, 0, stream>>>(part0, nbs0);
    k_scan3a<<<nbs0, 256, 0, stream>>>(rp0, part0, N0, E0);
    k_fill0<<<g0f, 256, 0, stream>>>(row0, col0, ew0, rank0, dinv0, rp0, ed0, E0, N0);

    // gather1 (x1) || hist g1 || hist cover
    k_gather_hist<<<G0 + nbE1 + nbC, 256, 0, stream>>>(
        xw, N0, rp0, ed0, dinv0, b_in1, x1, G0,
        col1, ew1, dc1, rank1, E1, nbE1, ccol, ccnt, rankc, A);

    // gemm2 (x1 -> xw) || scan1 g1 + dinv1 || scan1 cover
    k_gemm_scan<<<nbG0 + nbs1 + nbsc, 256, 0, stream>>>(
        x1, wpk + 16384, (unsigned short*)xw, N0, nbG0,
        dc1, rp1, part1, dinv1, N1, nbs1, ccnt, crp, cpart, N1);

    k_scan2b<<<2, 256, 0, stream>>>(part1, nbs1, cpart, nbsc);
    k_scan3b<<<nbs1 + nbsc, 256, 0, stream>>>(rp1, part1, N1, E1, nbs1, crp, cpart, N1, A);

    // gather2 (x2) || fill g1 || fill cover
    k_gather_fill<<<G0 + g1f + gcf, 256, 0, stream>>>(
        xw, N0, rp0, ed0, dinv0, b_in2, x2, G0,
        row1, col1, ew1, rank1, dinv1, rp1, ed1, E1, N1, g1f,
        crow, ccol, rankc, crp, csrcs, A);

    // gemm3: h = relu([x1,x2]@w_inl + b_inl)
    k_mfma_gemm<256, false><<<nbG0, 256, 0, stream>>>(
        x1, 128, (const unsigned short*)x2, 128, wpk + 32768, b_inl, 1,
        (unsigned short*)h, N0);

    // pool(g0) + cover gather
    k_pool_cover<<<B * NSPLIT + cdiv(N1, 4), 256, 0, stream>>>(
        (const unsigned short*)h, bst0, p0s, p0m, NSPLIT, B * NSPLIT,
        h, crp, csrcs, h2, N1);

    // block1
    k_mfma_gemm<256, false><<<nbG1, 256, 0, stream>>>(
        h2, 256, (const unsigned short*)h2 + 128, 256, wpk + 65536, nullptr, 0,
        (unsigned short*)xw, N1);
    k_gather<<<G1, 256, 0, stream>>>(xw, N1, rp1, ed1, dinv1, b_b1, x1);
    k_mfma_gemm<128, false><<<nbG1, 256, 0, stream>>>(
        x1, 128, nullptr, 0, wpk + 98304, nullptr, 0, (unsigned short*)xw, N1);
    k_gather<<<G1, 256, 0, stream>>>(xw, N1, rp1, ed1, dinv1, b_b2, x2);
    k_mfma_gemm<256, false><<<nbG1, 256, 0, stream>>>(
        x1, 128, (const unsigned short*)x2, 128, wpk + 114688, b_bl, 1,
        (unsigned short*)h, N1);

    k_pool256<<<B * NSPLIT, 256, 0, stream>>>((const unsigned short*)h, bst1, p1s, p1m, NSPLIT);

    k_head<<<B, 128, 0, stream>>>(p0s, p0m, p1s, p1m, gamma, beta, w_l1, b_l1, w_l2, b_l2,
                                  (float*)d_out);
}

// Round 14
// 364.586 us; speedup vs baseline: 1.0967x; 1.0967x over previous
//
#include <hip/hip_runtime.h>
#include <cmath>

#define HF 128
#define EPB 2048

namespace {

typedef __attribute__((ext_vector_type(8))) short short8;
typedef __attribute__((ext_vector_type(4))) float f32x4;
typedef unsigned long long u64;

inline int cdiv(int a, int b) { return (a + b - 1) / b; }

__device__ inline unsigned short f2bf(float x) {
    unsigned u = __float_as_uint(x);
    return (unsigned short)((u + 0x7fffu + ((u >> 16) & 1u)) >> 16);
}
__device__ inline float bf2f(unsigned short u) {
    return __uint_as_float((unsigned)u << 16);
}
__device__ inline float bflo(unsigned v) { return __uint_as_float(v << 16); }
__device__ inline float bfhi(unsigned v) { return __uint_as_float(v & 0xffff0000u); }

#define FIXS 4194304.0f            /* 2^22 */
#define FIXINV 2.384185791015625e-07f
#define SUMMASK ((1ULL << 40) - 1)

// ---- MFMA GEMM body: out[N,128](bf16) = [A1|A2][N,K] @ Wpk (+bias)(+relu) ----
template <int K, bool AF32>
__device__ __forceinline__ void gemm_dev(int bid, const void* __restrict__ A1v, int lda1,
                                         const void* __restrict__ A2v, int lda2,
                                         const unsigned short* __restrict__ wpk,
                                         const float* __restrict__ bias, int relu,
                                         unsigned short* __restrict__ out, int N) {
    const int t = threadIdx.x;
    const int wv = t >> 6, lane = t & 63;
    const int l15 = lane & 15, lhi = lane >> 4;
    const int rbase = bid * 128 + wv * 32;

    f32x4 acc[2][8];
#pragma unroll
    for (int i = 0; i < 2; ++i)
#pragma unroll
        for (int g = 0; g < 8; ++g) acc[i][g] = {0.f, 0.f, 0.f, 0.f};

    int r[2];
#pragma unroll
    for (int ri = 0; ri < 2; ++ri) {
        int rr = rbase + ri * 16 + l15;
        r[ri] = (rr < N) ? rr : (N - 1);
    }

    for (int kc = 0; kc < K / 32; ++kc) {
        int kb = kc * 32 + lhi * 8;
        short8 a[2];
#pragma unroll
        for (int ri = 0; ri < 2; ++ri) {
            if (AF32) {
                const float* A = (const float*)A1v;
                const float* p = A + (size_t)r[ri] * lda1 + kb;
                float4 f0 = *reinterpret_cast<const float4*>(p);
                float4 f1 = *reinterpret_cast<const float4*>(p + 4);
                a[ri][0] = (short)f2bf(f0.x); a[ri][1] = (short)f2bf(f0.y);
                a[ri][2] = (short)f2bf(f0.z); a[ri][3] = (short)f2bf(f0.w);
                a[ri][4] = (short)f2bf(f1.x); a[ri][5] = (short)f2bf(f1.y);
                a[ri][6] = (short)f2bf(f1.z); a[ri][7] = (short)f2bf(f1.w);
            } else {
                const unsigned short* base;
                int kk, ld;
                if (K == 256 && kb >= 128) { base = (const unsigned short*)A2v; kk = kb - 128; ld = lda2; }
                else                       { base = (const unsigned short*)A1v; kk = kb;       ld = lda1; }
                a[ri] = *reinterpret_cast<const short8*>(base + (size_t)r[ri] * ld + kk);
            }
        }
        const unsigned short* wb = wpk + (size_t)(kc * 8) * 512 + lane * 8;
#pragma unroll
        for (int g = 0; g < 8; ++g) {
            short8 b = *reinterpret_cast<const short8*>(wb + (size_t)g * 512);
            acc[0][g] = __builtin_amdgcn_mfma_f32_16x16x32_bf16(a[0], b, acc[0][g], 0, 0, 0);
            acc[1][g] = __builtin_amdgcn_mfma_f32_16x16x32_bf16(a[1], b, acc[1][g], 0, 0, 0);
        }
    }

#pragma unroll
    for (int ri = 0; ri < 2; ++ri) {
#pragma unroll
        for (int g = 0; g < 8; ++g) {
            int col = l15 + g * 16;
            float bb = bias ? bias[col] : 0.f;
#pragma unroll
            for (int e = 0; e < 4; ++e) {
                int rr = rbase + ri * 16 + lhi * 4 + e;
                if (rr < N) {
                    float v = acc[ri][g][e] + bb;
                    if (relu) v = fmaxf(v, 0.f);
                    out[(size_t)rr * 128 + col] = f2bf(v);
                }
            }
        }
    }
}

template <int K, bool AF32>
__global__ void k_mfma_gemm(const void* __restrict__ A1v, int lda1,
                            const void* __restrict__ A2v, int lda2,
                            const unsigned short* __restrict__ wpk,
                            const float* __restrict__ bias, int relu,
                            unsigned short* __restrict__ out, int N) {
    gemm_dev<K, AF32>(blockIdx.x, A1v, lda1, A2v, lda2, wpk, bias, relu, out, N);
}

// ---- device pieces ----
__device__ __forceinline__ void hist_dev(int e, int E, const int* __restrict__ col,
                                         const float* __restrict__ ew,
                                         u64* __restrict__ dc, unsigned* __restrict__ rank) {
    if (e < E) {
        u64 v = (1ULL << 40) | (u64)(ew[e] * FIXS + 0.5f);
        u64 old = atomicAdd(&dc[col[e]], v);
        rank[e] = (unsigned)(old >> 40);
    }
}

__device__ inline void scan256(int* s, int v, int gid, int n, int* __restrict__ excl,
                               int* __restrict__ partial, int pb) {
    s[threadIdx.x] = v;
    __syncthreads();
    for (int off = 1; off < 256; off <<= 1) {
        int t = (threadIdx.x >= off) ? s[threadIdx.x - off] : 0;
        __syncthreads();
        s[threadIdx.x] += t;
        __syncthreads();
    }
    if (gid < n) excl[gid] = s[threadIdx.x] - v;
    if (threadIdx.x == 255) partial[pb] = s[255];
}

// packed CSR record: {coef_bf16:16 | src:16}; coef = ew * dinv[src]
__device__ __forceinline__ void fill_dev(int b, int t, const int* __restrict__ row,
                                         const int* __restrict__ col, const float* __restrict__ ew,
                                         const unsigned* __restrict__ rank,
                                         const float* __restrict__ dinv, const int* __restrict__ rp,
                                         unsigned* __restrict__ ed, int E, int Nn) {
    int xcd = b & 7, chunk = b >> 3;
    int lo = (int)((long long)Nn * xcd >> 3), hi = (int)((long long)Nn * (xcd + 1) >> 3);
    int base = chunk * EPB;
#pragma unroll
    for (int i = 0; i < EPB; i += 256) {
        int e = base + i + t;
        if (e < E) {
            int c = col[e];
            if (c >= lo && c < hi) {
                int r = row[e];
                ed[rp[c] + rank[e]] =
                    (unsigned)r | ((unsigned)f2bf(ew[e] * dinv[r]) << 16);
            }
        }
    }
}

// gather: one wave/dest; 8-deep row-load pipeline.
// acc = dinv*xw[c] + sum coef*xw[src]; out = relu(acc*dinv + b)
__device__ __forceinline__ void gather_dev(int b, const unsigned* __restrict__ xw, int n,
                                           const int* __restrict__ rp,
                                           const unsigned* __restrict__ ed,
                                           const float* __restrict__ dinv,
                                           const float* __restrict__ bias,
                                           unsigned* __restrict__ out) {
    int wid = (b * 256 + (int)threadIdx.x) >> 6;
    if (wid >= n) return;
    int lane = threadIdx.x & 63;
    int s = rp[wid], e = rp[wid + 1];
    float d = dinv[wid];
    unsigned v = xw[(size_t)wid * 64 + lane];
    float ax = bflo(v) * d, ay = bfhi(v) * d;
    float bx = 0.f, by = 0.f, cx = 0.f, cy = 0.f, dx = 0.f, dy = 0.f;
    float ex = 0.f, ey = 0.f, fx = 0.f, fy = 0.f, gx = 0.f, gy = 0.f, hx = 0.f, hy = 0.f;
    int i = s;
    for (; (i & 3) != 0 && i < e; ++i) {
        unsigned q = ed[i];
        unsigned v0 = xw[(size_t)(q & 0xffffu) * 64 + lane];
        float c0 = bfhi(q);
        ax += c0 * bflo(v0); ay += c0 * bfhi(v0);
    }
    for (; i + 8 <= e; i += 8) {
        uint4 q0 = *reinterpret_cast<const uint4*>(ed + i);
        uint4 q1 = *reinterpret_cast<const uint4*>(ed + i + 4);
        unsigned v0 = xw[(size_t)(q0.x & 0xffffu) * 64 + lane];
        unsigned v1 = xw[(size_t)(q0.y & 0xffffu) * 64 + lane];
        unsigned v2 = xw[(size_t)(q0.z & 0xffffu) * 64 + lane];
        unsigned v3 = xw[(size_t)(q0.w & 0xffffu) * 64 + lane];
        unsigned v4 = xw[(size_t)(q1.x & 0xffffu) * 64 + lane];
        unsigned v5 = xw[(size_t)(q1.y & 0xffffu) * 64 + lane];
        unsigned v6 = xw[(size_t)(q1.z & 0xffffu) * 64 + lane];
        unsigned v7 = xw[(size_t)(q1.w & 0xffffu) * 64 + lane];
        float c0 = bfhi(q0.x), c1 = bfhi(q0.y), c2 = bfhi(q0.z), c3 = bfhi(q0.w);
        float c4 = bfhi(q1.x), c5 = bfhi(q1.y), c6 = bfhi(q1.z), c7 = bfhi(q1.w);
        ax += c0 * bflo(v0); ay += c0 * bfhi(v0);
        bx += c1 * bflo(v1); by += c1 * bfhi(v1);
        cx += c2 * bflo(v2); cy += c2 * bfhi(v2);
        dx += c3 * bflo(v3); dy += c3 * bfhi(v3);
        ex += c4 * bflo(v4); ey += c4 * bfhi(v4);
        fx += c5 * bflo(v5); fy += c5 * bfhi(v5);
        gx += c6 * bflo(v6); gy += c6 * bfhi(v6);
        hx += c7 * bflo(v7); hy += c7 * bfhi(v7);
    }
    if (i + 4 <= e) {
        uint4 q0 = *reinterpret_cast<const uint4*>(ed + i);
        unsigned v0 = xw[(size_t)(q0.x & 0xffffu) * 64 + lane];
        unsigned v1 = xw[(size_t)(q0.y & 0xffffu) * 64 + lane];
        unsigned v2 = xw[(size_t)(q0.z & 0xffffu) * 64 + lane];
        unsigned v3 = xw[(size_t)(q0.w & 0xffffu) * 64 + lane];
        float c0 = bfhi(q0.x), c1 = bfhi(q0.y), c2 = bfhi(q0.z), c3 = bfhi(q0.w);
        ax += c0 * bflo(v0); ay += c0 * bfhi(v0);
        bx += c1 * bflo(v1); by += c1 * bfhi(v1);
        cx += c2 * bflo(v2); cy += c2 * bfhi(v2);
        dx += c3 * bflo(v3); dy += c3 * bfhi(v3);
        i += 4;
    }
    for (; i < e; ++i) {
        unsigned q = ed[i];
        unsigned v0 = xw[(size_t)(q & 0xffffu) * 64 + lane];
        float c0 = bfhi(q);
        ax += c0 * bflo(v0); ay += c0 * bfhi(v0);
    }
    ax += bx + cx + dx + ex + fx + gx + hx;
    ay += by + cy + dy + ey + fy + gy + hy;
    float2 bb = *reinterpret_cast<const float2*>(bias + lane * 2);
    ax = fmaxf(ax * d + bb.x, 0.f);
    ay = fmaxf(ay * d + bb.y, 0.f);
    out[(size_t)wid * 64 + lane] = (unsigned)f2bf(ax) | ((unsigned)f2bf(ay) << 16);
}

// ---- kernels ----
// K0: pack_w + bstart
__global__ void k_prep0(const float* __restrict__ w0, const float* __restrict__ w1,
                        const float* __restrict__ w2, const float* __restrict__ w3,
                        const float* __restrict__ w4, const float* __restrict__ w5,
                        unsigned short* __restrict__ wpk,
                        const int* __restrict__ b0, int n0, const int* __restrict__ b1,
                        int n1, int B, int* __restrict__ bst0, int* __restrict__ bst1) {
    int b = blockIdx.x, t = threadIdx.x;
    if (b < 576) {
        int idx = b * 256 + t;
        const float* src; int local;
        if      (idx < 16384)  { src = w0; local = idx; }
        else if (idx < 32768)  { src = w1; local = idx - 16384; }
        else if (idx < 65536)  { src = w2; local = idx - 32768; }
        else if (idx < 98304)  { src = w3; local = idx - 65536; }
        else if (idx < 114688) { src = w4; local = idx - 98304; }
        else                   { src = w5; local = idx - 114688; }
        int e = local & 7, lane = (local >> 3) & 63, g = (local >> 9) & 7, kc = local >> 12;
        int colw = (lane & 15) + 16 * g;
        int k = kc * 32 + ((lane >> 4) << 3) + e;
        wpk[idx] = f2bf(src[k * 128 + colw]);
        return;
    }
    int idx = t;
    if (idx < 2 * (B + 1)) {
        int which = idx > B;
        int bb = which ? idx - (B + 1) : idx;
        const int* arr = which ? b1 : b0;
        int lo = 0, hi = which ? n1 : n0;
        while (lo < hi) {
            int mid = (lo + hi) >> 1;
            if (arr[mid] < bb) lo = mid + 1; else hi = mid;
        }
        (which ? bst1 : bst0)[bb] = lo;
    }
}

// K1: GEMM1 || hist g0
__global__ void k_prep1(const float* __restrict__ x, const unsigned short* __restrict__ wpk,
                        unsigned short* __restrict__ xw, int N0gemm, int nbG,
                        const int* __restrict__ col0, const float* __restrict__ ew0,
                        u64* __restrict__ dc0, unsigned* __restrict__ rank0, int E0) {
    int b = blockIdx.x;
    if (b < nbG) {
        gemm_dev<128, true>(b, x, 128, nullptr, 0, wpk, nullptr, 0, xw, N0gemm);
        return;
    }
    b -= nbG;
    hist_dev(b * 256 + (int)threadIdx.x, E0, col0, ew0, dc0, rank0);
}

// K2: scan1(g0) + dinv0
__global__ void k_scanA(const u64* __restrict__ dc0, int* __restrict__ rp0,
                        int* __restrict__ part0, float* __restrict__ dinv0, int n0) {
    __shared__ int s[256];
    int gid = blockIdx.x * 256 + threadIdx.x;
    int v = (gid < n0) ? (int)(dc0[gid] >> 40) : 0;
    scan256(s, v, gid, n0, rp0, part0, blockIdx.x);
    if (gid < n0) dinv0[gid] = rsqrtf(1.0f + (float)(dc0[gid] & SUMMASK) * FIXINV);
}

__global__ void k_scan2a(int* __restrict__ p0, int nb0) {
    __shared__ int s[256];
    int v = (threadIdx.x < nb0) ? p0[threadIdx.x] : 0;
    s[threadIdx.x] = v;
    __syncthreads();
    for (int off = 1; off < 256; off <<= 1) {
        int t = (threadIdx.x >= off) ? s[threadIdx.x - off] : 0;
        __syncthreads();
        s[threadIdx.x] += t;
        __syncthreads();
    }
    if (threadIdx.x < nb0) p0[threadIdx.x] = s[threadIdx.x] - v;
}

__global__ void k_scan3a(int* __restrict__ rp0, const int* __restrict__ part0, int n0, int tot) {
    int gid = blockIdx.x * 256 + threadIdx.x;
    if (gid < n0) rp0[gid] += part0[blockIdx.x];
    if (gid == 0) rp0[n0] = tot;
}

// fill g0
__global__ void k_fill0(const int* __restrict__ row0, const int* __restrict__ col0,
                        const float* __restrict__ ew0, const unsigned* __restrict__ rank0,
                        const float* __restrict__ dinv0, const int* __restrict__ rp0,
                        unsigned* __restrict__ ed0, int E0, int N0n) {
    fill_dev(blockIdx.x, threadIdx.x, row0, col0, ew0, rank0, dinv0, rp0, ed0, E0, N0n);
}

// gather1 + hist(g1) + hist(cover)
__global__ void k_gather_hist(const unsigned* __restrict__ xw, int n,
                              const int* __restrict__ rp, const unsigned* __restrict__ ed,
                              const float* __restrict__ dinv, const float* __restrict__ bias,
                              unsigned* __restrict__ out, int G,
                              const int* __restrict__ col1, const float* __restrict__ ew1,
                              u64* __restrict__ dc1, unsigned* __restrict__ rank1,
                              int E1, int nb1,
                              const int* __restrict__ ccol, int* __restrict__ ccnt,
                              unsigned* __restrict__ rankc, int A) {
    int b = blockIdx.x;
    if (b < G) { gather_dev(b, xw, n, rp, ed, dinv, bias, out); return; }
    b -= G;
    int t = threadIdx.x;
    if (b < nb1) { hist_dev(b * 256 + t, E1, col1, ew1, dc1, rank1); return; }
    b -= nb1;
    int e = b * 256 + t;
    if (e < A) rankc[e] = (unsigned)atomicAdd(&ccnt[ccol[e]], 1);
}

// gemm2 + scan1(g1)+dinv1 + scan1(cover)
__global__ void k_gemm_scan(const void* __restrict__ A1v, const unsigned short* __restrict__ wpk,
                            unsigned short* __restrict__ out, int N, int nbG,
                            const u64* __restrict__ dc1, int* __restrict__ rp1,
                            int* __restrict__ part1, float* __restrict__ dinv1, int n1, int nbs1,
                            const int* __restrict__ ccnt, int* __restrict__ crp,
                            int* __restrict__ cpart, int nc) {
    __shared__ int s[256];
    int b = blockIdx.x;
    if (b < nbG) {
        gemm_dev<128, false>(b, A1v, 128, nullptr, 0, wpk, nullptr, 0, out, N);
        return;
    }
    b -= nbG;
    if (b < nbs1) {
        int gid = b * 256 + threadIdx.x;
        int v = (gid < n1) ? (int)(dc1[gid] >> 40) : 0;
        scan256(s, v, gid, n1, rp1, part1, b);
        if (gid < n1) dinv1[gid] = rsqrtf(1.0f + (float)(dc1[gid] & SUMMASK) * FIXINV);
        return;
    }
    b -= nbs1;
    {
        int gid = b * 256 + threadIdx.x;
        int v = (gid < nc) ? ccnt[gid] : 0;
        scan256(s, v, gid, nc, crp, cpart, b);
    }
}

__global__ void k_scan2b(int* __restrict__ p1, int nb1, int* __restrict__ p2, int nb2) {
    __shared__ int s[256];
    int* p = (blockIdx.x == 0) ? p1 : p2;
    int nb = (blockIdx.x == 0) ? nb1 : nb2;
    int v = (threadIdx.x < nb) ? p[threadIdx.x] : 0;
    s[threadIdx.x] = v;
    __syncthreads();
    for (int off = 1; off < 256; off <<= 1) {
        int t = (threadIdx.x >= off) ? s[threadIdx.x - off] : 0;
        __syncthreads();
        s[threadIdx.x] += t;
        __syncthreads();
    }
    if (threadIdx.x < nb) p[threadIdx.x] = s[threadIdx.x] - v;
}

__global__ void k_scan3b(int* __restrict__ rp1, const int* __restrict__ part1, int n1, int tot1,
                         int nb1, int* __restrict__ crp, const int* __restrict__ cpart,
                         int nc, int totc) {
    int b = blockIdx.x, t = threadIdx.x;
    if (b < nb1) {
        int gid = b * 256 + t;
        if (gid < n1) rp1[gid] += part1[b];
        if (gid == 0) rp1[n1] = tot1;
        return;
    }
    b -= nb1;
    int gid = b * 256 + t;
    if (gid < nc) crp[gid] += cpart[b];
    if (gid == 0) crp[nc] = totc;
}

// gather2 + fill(g1) + fill(cover, u16 srcs)
__global__ void k_gather_fill(const unsigned* __restrict__ xw, int n,
                              const int* __restrict__ rp, const unsigned* __restrict__ ed,
                              const float* __restrict__ dinv, const float* __restrict__ bias,
                              unsigned* __restrict__ out, int G,
                              const int* __restrict__ row1, const int* __restrict__ col1,
                              const float* __restrict__ ew1, const unsigned* __restrict__ rank1,
                              const float* __restrict__ dinv1, const int* __restrict__ rp1,
                              unsigned* __restrict__ ed1, int E1, int N1n, int g1b,
                              const int* __restrict__ crow, const int* __restrict__ ccol,
                              const unsigned* __restrict__ rankc, const int* __restrict__ crp,
                              unsigned short* __restrict__ csrcs, int A) {
    int b = blockIdx.x, t = threadIdx.x;
    if (b < G) { gather_dev(b, xw, n, rp, ed, dinv, bias, out); return; }
    b -= G;
    if (b < g1b) { fill_dev(b, t, row1, col1, ew1, rank1, dinv1, rp1, ed1, E1, N1n); return; }
    b -= g1b;
    {
        int xcd = b & 7, chunk = b >> 3;
        int lo = (int)((long long)N1n * xcd >> 3), hi = (int)((long long)N1n * (xcd + 1) >> 3);
        int base = chunk * EPB;
#pragma unroll
        for (int i = 0; i < EPB; i += 256) {
            int e = base + i + t;
            if (e < A) {
                int c = ccol[e];
                if (c >= lo && c < hi) csrcs[crp[c] + rankc[e]] = (unsigned short)crow[e];
            }
        }
    }
}

// plain gather
__global__ void k_gather(const unsigned* __restrict__ xw, int n, const int* __restrict__ rp,
                         const unsigned* __restrict__ ed, const float* __restrict__ dinv,
                         const float* __restrict__ bias, unsigned* __restrict__ out) {
    gather_dev(blockIdx.x, xw, n, rp, ed, dinv, bias, out);
}

// fused: batch pool (g0) + cover gather; h bf16 >= 0
__global__ void k_pool_cover(const unsigned short* __restrict__ h, const int* __restrict__ bst,
                             float* __restrict__ psum, float* __restrict__ pmax, int nsplit,
                             int nbpool, const unsigned* __restrict__ h32,
                             const int* __restrict__ crp,
                             const unsigned short* __restrict__ csrcs,
                             unsigned* __restrict__ h2, int n1) {
    int t = threadIdx.x;
    if ((int)blockIdx.x < nbpool) {
        int blk = blockIdx.x;
        int b = blk / nsplit, sub = (blk % nsplit) * 2 + (t >> 7);
        int col = t & 127;
        int r0 = bst[b], r1 = bst[b + 1];
        float sum = 0.f, mx = 0.f;
        for (int r = r0 + sub; r < r1; r += 2 * nsplit) {
            float v = bf2f(h[(size_t)r * HF + col]);
            sum += v;
            mx = fmaxf(mx, v);
        }
        atomicAdd(&psum[b * HF + col], sum);
        atomicMax(reinterpret_cast<int*>(&pmax[b * HF + col]), __float_as_int(mx));
        return;
    }
    int wid = (((int)blockIdx.x - nbpool) * 256 + t) >> 6;
    if (wid >= n1) return;
    int lane = t & 63;
    int s = crp[wid], e = crp[wid + 1];
    float sx = 0.f, sy = 0.f, mx = 0.f, my = 0.f;
    for (int i = s; i < e; ++i) {
        unsigned v = h32[(size_t)csrcs[i] * 64 + lane];
        float vx = bflo(v), vy = bfhi(v);
        sx += vx; sy += vy;
        mx = fmaxf(mx, vx); my = fmaxf(my, vy);
    }
    h2[(size_t)wid * 128 + lane]      = (unsigned)f2bf(sx) | ((unsigned)f2bf(sy) << 16);
    h2[(size_t)wid * 128 + 64 + lane] = (unsigned)f2bf(mx) | ((unsigned)f2bf(my) << 16);
}

__global__ void k_pool256(const unsigned short* __restrict__ h, const int* __restrict__ bst,
                          float* __restrict__ psum, float* __restrict__ pmax, int nsplit) {
    int t = threadIdx.x;
    int blk = blockIdx.x;
    int b = blk / nsplit, sub = (blk % nsplit) * 2 + (t >> 7);
    int col = t & 127;
    int r0 = bst[b], r1 = bst[b + 1];
    float sum = 0.f, mx = 0.f;
    for (int r = r0 + sub; r < r1; r += 2 * nsplit) {
        float v = bf2f(h[(size_t)r * HF + col]);
        sum += v;
        mx = fmaxf(mx, v);
    }
    atomicAdd(&psum[b * HF + col], sum);
    atomicMax(reinterpret_cast<int*>(&pmax[b * HF + col]), __float_as_int(mx));
}

__global__ void k_head(const float* __restrict__ p0s, const float* __restrict__ p0m,
                       const float* __restrict__ p1s, const float* __restrict__ p1m,
                       const float* __restrict__ gamma, const float* __restrict__ beta,
                       const float* __restrict__ w1, const float* __restrict__ b1,
                       const float* __restrict__ w2, const float* __restrict__ b2,
                       float* __restrict__ out) {
    __shared__ float z[512];
    __shared__ float z1[128];
    __shared__ float lg[10];
    int b = blockIdx.x, t = threadIdx.x;
    const float s = rsqrtf(1.0f + 1e-5f);
    z[t]       = p0s[b * 128 + t] * (gamma[t] * s)       + beta[t];
    z[128 + t] = p0m[b * 128 + t] * (gamma[128 + t] * s) + beta[128 + t];
    z[256 + t] = p1s[b * 128 + t] * (gamma[256 + t] * s) + beta[256 + t];
    z[384 + t] = p1m[b * 128 + t] * (gamma[384 + t] * s) + beta[384 + t];
    __syncthreads();
    float acc = b1[t];
    for (int k = 0; k < 512; ++k) acc += z[k] * w1[k * 128 + t];
    z1[t] = fmaxf(acc, 0.f);
    __syncthreads();
    if (t < 10) {
        float a2 = b2[t];
        for (int k = 0; k < 128; ++k) a2 += z1[k] * w2[k * 10 + t];
        lg[t] = a2;
    }
    __syncthreads();
    if (t == 0) {
        float m = lg[0];
        for (int c = 1; c < 10; ++c) m = fmaxf(m, lg[c]);
        float e[10], ssum = 0.f;
        for (int c = 0; c < 10; ++c) { e[c] = expf(lg[c] - m); ssum += e[c]; }
        for (int c = 0; c < 10; ++c) out[b * 10 + c] = e[c] / ssum;
    }
}

} // namespace

extern "C" void kernel_launch(void* const* d_in, const int* in_sizes, int n_in,
                              void* d_out, int out_size, void* d_ws, size_t ws_size,
                              hipStream_t stream) {
    const float* x      = (const float*)d_in[0];
    const int*   ei0    = (const int*)d_in[1];
    const float* ew0    = (const float*)d_in[2];
    const int*   batch0 = (const int*)d_in[3];
    const int*   crow   = (const int*)d_in[4];
    const int*   ccol   = (const int*)d_in[5];
    const int*   ei1    = (const int*)d_in[6];
    const float* ew1    = (const float*)d_in[7];
    const int*   batch1 = (const int*)d_in[8];
    const float* w_in1  = (const float*)d_in[9];
    const float* b_in1  = (const float*)d_in[10];
    const float* w_in2  = (const float*)d_in[11];
    const float* b_in2  = (const float*)d_in[12];
    const float* w_inl  = (const float*)d_in[13];
    const float* b_inl  = (const float*)d_in[14];
    const float* w_b1   = (const float*)d_in[15];
    const float* b_b1   = (const float*)d_in[16];
    const float* w_b2   = (const float*)d_in[17];
    const float* b_b2   = (const float*)d_in[18];
    const float* w_bl   = (const float*)d_in[19];
    const float* b_bl   = (const float*)d_in[20];
    const float* gamma  = (const float*)d_in[21];
    const float* beta   = (const float*)d_in[22];
    const float* w_l1   = (const float*)d_in[23];
    const float* b_l1   = (const float*)d_in[24];
    const float* w_l2   = (const float*)d_in[25];
    const float* b_l2   = (const float*)d_in[26];

    const int N0 = in_sizes[0] / 128;
    const int E0 = in_sizes[2];
    const int A  = in_sizes[4];
    const int E1 = in_sizes[7];
    const int N1 = in_sizes[8];
    const int B  = out_size / 10;

    const int* row0 = ei0;
    const int* col0 = ei0 + E0;
    const int* row1 = ei1;
    const int* col1 = ei1 + E1;

    // ---- workspace layout ----
    char* wsp = (char*)d_ws;
    size_t off = 0;
    auto alloc = [&](size_t bytes) -> char* {
        char* p = wsp + off;
        off += (bytes + 255) & ~(size_t)255;
        return p;
    };
    // zero region: dc0, dc1, ccnt, pools
    u64*  dc0  = (u64*)alloc((size_t)N0 * 8);
    u64*  dc1  = (u64*)alloc((size_t)N1 * 8);
    int*  ccnt = (int*)alloc((size_t)N1 * 4);
    float* p0s = (float*)alloc((size_t)B * HF * 4 * 4);
    float* p0m = p0s + (size_t)B * HF;
    float* p1s = p0m + (size_t)B * HF;
    float* p1m = p1s + (size_t)B * HF;
    size_t zero_bytes = off;

    unsigned* xw  = (unsigned*)alloc((size_t)N0 * 64 * 4);
    unsigned* x1  = (unsigned*)alloc((size_t)N0 * 64 * 4);
    unsigned* x2  = (unsigned*)alloc((size_t)N0 * 64 * 4);
    unsigned* h   = (unsigned*)alloc((size_t)N0 * 64 * 4);
    unsigned* h2  = (unsigned*)alloc((size_t)N1 * 128 * 4);
    unsigned short* wpk = (unsigned short*)alloc(147456 * 2);
    float* dinv0 = (float*)alloc((size_t)N0 * 4);
    float* dinv1 = (float*)alloc((size_t)N1 * 4);
    int*   rp0   = (int*)alloc(((size_t)N0 + 1) * 4);
    int*   rp1   = (int*)alloc(((size_t)N1 + 1) * 4);
    int*   crp   = (int*)alloc(((size_t)N1 + 1) * 4);
    int*   part0 = (int*)alloc(256 * 4);
    int*   part1 = (int*)alloc(256 * 4);
    int*   cpart = (int*)alloc(256 * 4);
    unsigned* ed0 = (unsigned*)alloc((size_t)E0 * 4);
    unsigned* ed1 = (unsigned*)alloc((size_t)E1 * 4);
    unsigned short* csrcs = (unsigned short*)alloc((size_t)A * 2);
    unsigned* rank0 = (unsigned*)alloc((size_t)E0 * 4);
    unsigned* rank1 = (unsigned*)alloc((size_t)E1 * 4);
    unsigned* rankc = (unsigned*)alloc((size_t)A * 4);
    int*   bst0  = (int*)alloc((size_t)(B + 1) * 4);
    int*   bst1  = (int*)alloc((size_t)(B + 1) * 4);
    (void)ws_size; (void)n_in;

    const int NSPLIT = 16;
    const int nbG0 = cdiv(N0, 128), nbG1 = cdiv(N1, 128);
    const int nbE0 = cdiv(E0, 256), nbE1 = cdiv(E1, 256), nbC = cdiv(A, 256);
    const int nbs0 = cdiv(N0, 256), nbs1 = cdiv(N1, 256), nbsc = cdiv(N1, 256);
    const int g0f = cdiv(E0, EPB) * 8, g1f = cdiv(E1, EPB) * 8, gcf = cdiv(A, EPB) * 8;
    const int G0 = cdiv(N0, 4), G1 = cdiv(N1, 4);

    hipMemsetAsync(dc0, 0, zero_bytes, stream);

    k_prep0<<<577, 256, 0, stream>>>(w_in1, w_in2, w_inl, w_b1, w_b2, w_bl, wpk,
                                     batch0, N0, batch1, N1, B, bst0, bst1);

    // GEMM1 || hist g0
    k_prep1<<<nbG0 + nbE0, 256, 0, stream>>>(x, wpk, (unsigned short*)xw, N0, nbG0,
                                             col0, ew0, dc0, rank0, E0);

    k_scanA<<<nbs0, 256, 0, stream>>>(dc0, rp0, part0, dinv0, N0);
    k_scan2a<<<1, 256, 0, stream>>>(part0, nbs0);
    k_scan3a<<<nbs0, 256, 0, stream>>>(rp0, part0, N0, E0);
    k_fill0<<<g0f, 256, 0, stream>>>(row0, col0, ew0, rank0, dinv0, rp0, ed0, E0, N0);

    // gather1 (x1) || hist g1 || hist cover
    k_gather_hist<<<G0 + nbE1 + nbC, 256, 0, stream>>>(
        xw, N0, rp0, ed0, dinv0, b_in1, x1, G0,
        col1, ew1, dc1, rank1, E1, nbE1, ccol, ccnt, rankc, A);

    // gemm2 (x1 -> xw) || scan1 g1 + dinv1 || scan1 cover
    k_gemm_scan<<<nbG0 + nbs1 + nbsc, 256, 0, stream>>>(
        x1, wpk + 16384, (unsigned short*)xw, N0, nbG0,
        dc1, rp1, part1, dinv1, N1, nbs1, ccnt, crp, cpart, N1);

    k_scan2b<<<2, 256, 0, stream>>>(part1, nbs1, cpart, nbsc);
    k_scan3b<<<nbs1 + nbsc, 256, 0, stream>>>(rp1, part1, N1, E1, nbs1, crp, cpart, N1, A);

    // gather2 (x2) || fill g1 || fill cover
    k_gather_fill<<<G0 + g1f + gcf, 256, 0, stream>>>(
        xw, N0, rp0, ed0, dinv0, b_in2, x2, G0,
        row1, col1, ew1, rank1, dinv1, rp1, ed1, E1, N1, g1f,
        crow, ccol, rankc, crp, csrcs, A);

    // gemm3: h = relu([x1,x2]@w_inl + b_inl)
    k_mfma_gemm<256, false><<<nbG0, 256, 0, stream>>>(
        x1, 128, (const unsigned short*)x2, 128, wpk + 32768, b_inl, 1,
        (unsigned short*)h, N0);

    // pool(g0) + cover gather
    k_pool_cover<<<B * NSPLIT + cdiv(N1, 4), 256, 0, stream>>>(
        (const unsigned short*)h, bst0, p0s, p0m, NSPLIT, B * NSPLIT,
        h, crp, csrcs, h2, N1);

    // block1
    k_mfma_gemm<256, false><<<nbG1, 256, 0, stream>>>(
        h2, 256, (const unsigned short*)h2 + 128, 256, wpk + 65536, nullptr, 0,
        (unsigned short*)xw, N1);
    k_gather<<<G1, 256, 0, stream>>>(xw, N1, rp1, ed1, dinv1, b_b1, x1);
    k_mfma_gemm<128, false><<<nbG1, 256, 0, stream>>>(
        x1, 128, nullptr, 0, wpk + 98304, nullptr, 0, (unsigned short*)xw, N1);
    k_gather<<<G1, 256, 0, stream>>>(xw, N1, rp1, ed1, dinv1, b_b2, x2);
    k_mfma_gemm<256, false><<<nbG1, 256, 0, stream>>>(
        x1, 128, (const unsigned short*)x2, 128, wpk + 114688, b_bl, 1,
        (unsigned short*)h, N1);

    k_pool256<<<B * NSPLIT, 256, 0, stream>>>((const unsigned short*)h, bst1, p1s, p1m, NSPLIT);

    k_head<<<B, 128, 0, stream>>>(p0s, p0m, p1s, p1m, gamma, beta, w_l1, b_l1, w_l2, b_l2,
                                  (float*)d_out);
}